// Round 2
// baseline (539.722 us; speedup 1.0000x reference)
//
#include <hip/hip_runtime.h>
#include <cstdint>
#include <cstddef>

// ---------------------------------------------------------------------------
// Types / helpers
// ---------------------------------------------------------------------------
using f32x4  = __attribute__((ext_vector_type(4))) float;
using i32x4v = __attribute__((ext_vector_type(4))) int;
using i32x8v = __attribute__((ext_vector_type(8))) int;

__device__ __forceinline__ unsigned char f2fp8(float f) {
  return (unsigned char)(__builtin_amdgcn_cvt_pk_fp8_f32(f, f, 0, false) & 0xff);
}

// exact dequant of OCP e4m3fn byte (sel selects byte of w)
__device__ __forceinline__ float fp8b0(unsigned int w) {
  return __builtin_amdgcn_cvt_f32_fp8(w, 0);
}
__device__ __forceinline__ float fp8b1(unsigned int w) {
  return __builtin_amdgcn_cvt_f32_fp8(w, 1);
}
__device__ __forceinline__ float fp8b2(unsigned int w) {
  return __builtin_amdgcn_cvt_f32_fp8(w, 2);
}
__device__ __forceinline__ float fp8b3(unsigned int w) {
  return __builtin_amdgcn_cvt_f32_fp8(w, 3);
}

__device__ __forceinline__ float waveRed(float v) {
#pragma unroll
  for (int m = 32; m >= 1; m >>= 1) v += __shfl_xor(v, m, 64);
  return v;
}

// async global->LDS, 16B per lane. LDS dest must be wave-uniform base + lane*16.
__device__ __forceinline__ void gload16(const void* g, void* l) {
  __builtin_amdgcn_global_load_lds(
      (__attribute__((address_space(1))) uint32_t*)(uintptr_t)g,
      (__attribute__((address_space(3))) uint32_t*)(uint32_t*)l,
      16, 0, 0);
}

// ---------------------------------------------------------------------------
// prep_w: fused weight prep + workspace zeroing + b0 copy.
// blocks [0,1024)    : W1 -> fp8
// blocks [1024,1280) : W2 -> fp8
// blocks [1280,1536) : W0 -> fp8 row-major (Bcat8 seg0)
// blocks [1536,1792) : W0^T -> fp8 (LDS-tiled)
// blocks [1792,1792+zb) : zero zr region (zwords)
// blocks [1792+zb, +8)  : biascat[0..2047] = b0
// ---------------------------------------------------------------------------
__global__ __launch_bounds__(256) void prep_w(
    const float4* __restrict__ W1, const float4* __restrict__ W2,
    const float4* __restrict__ W0f4, const float* __restrict__ W0,
    const float* __restrict__ b0,
    uint32_t* __restrict__ W1_8, uint32_t* __restrict__ W2_8,
    uint32_t* __restrict__ W0_8, unsigned char* __restrict__ W0t8,
    float* __restrict__ zr, int zwords, float* __restrict__ biascat) {
  __shared__ unsigned char t8[64][65];
  const int b = blockIdx.x;
  const int tid = threadIdx.x;
  if (b < 1024) {
    for (int i = b * 256 + tid; i < 524288; i += 1024 * 256) {
      float4 v = W1[i];
      int p = __builtin_amdgcn_cvt_pk_fp8_f32(v.x, v.y, 0, false);
      p = __builtin_amdgcn_cvt_pk_fp8_f32(v.z, v.w, p, true);
      W1_8[i] = (uint32_t)p;
    }
  } else if (b < 1280) {
    for (int i = (b - 1024) * 256 + tid; i < 131072; i += 256 * 256) {
      float4 v = W2[i];
      int p = __builtin_amdgcn_cvt_pk_fp8_f32(v.x, v.y, 0, false);
      p = __builtin_amdgcn_cvt_pk_fp8_f32(v.z, v.w, p, true);
      W2_8[i] = (uint32_t)p;
    }
  } else if (b < 1536) {
    for (int i = (b - 1280) * 256 + tid; i < 262144; i += 256 * 256) {
      float4 v = W0f4[i];
      int p = __builtin_amdgcn_cvt_pk_fp8_f32(v.x, v.y, 0, false);
      p = __builtin_amdgcn_cvt_pk_fp8_f32(v.z, v.w, p, true);
      W0_8[i] = (uint32_t)p;
    }
  } else if (b < 1792) {
    // transpose W0 (2048 x 512 fp32) -> W0t8 (512 x 2048 fp8)
    const int t = b - 1536;             // 32 row-tiles x 8 col-tiles
    const int r0 = (t >> 3) * 64, c0 = (t & 7) * 64;
#pragma unroll
    for (int p = 0; p < 16; ++p) {
      const int row = p * 4 + (tid >> 6), col = tid & 63;
      t8[row][col] = f2fp8(W0[(size_t)(r0 + row) * 512 + c0 + col]);
    }
    __syncthreads();
#pragma unroll
    for (int p = 0; p < 16; ++p) {
      const int oc = p * 4 + (tid >> 6), orr = tid & 63;
      W0t8[(size_t)(c0 + oc) * 2048 + r0 + orr] = t8[orr][oc];
    }
  } else {
    const int zb = (zwords + 255) >> 8;
    if (b < 1792 + zb) {
      const int i = (b - 1792) * 256 + tid;
      if (i < zwords) zr[i] = 0.f;
    } else {
      const int i = (b - 1792 - zb) * 256 + tid;
      if (i < 2048) biascat[i] = b0[i];
    }
  }
}

// LDS-histogram label count
__global__ __launch_bounds__(256) void count_k(const int* __restrict__ lab,
                                               int* __restrict__ counts, int n) {
  __shared__ int h[512];
  for (int i = threadIdx.x; i < 512; i += 256) h[i] = 0;
  __syncthreads();
  for (int i = blockIdx.x * 256 + threadIdx.x; i < n; i += gridDim.x * 256)
    atomicAdd(&h[lab[i]], 1);
  __syncthreads();
  for (int i = threadIdx.x; i < 512; i += 256) {
    int v = h[i];
    if (v) atomicAdd(&counts[i], v);
  }
}

// single-wave shuffle scan
__global__ void prefix_k(const int* __restrict__ counts, int* __restrict__ offsets,
                         int* __restrict__ cursor, int nc) {
  const int lane = threadIdx.x;  // 64 threads
  int base = 0;
  for (int c0 = 0; c0 < nc; c0 += 64) {
    int v = counts[c0 + lane];
    int x = v;
#pragma unroll
    for (int d = 1; d < 64; d <<= 1) {
      int y = __shfl_up(x, d, 64);
      if (lane >= d) x += y;
    }
    int excl = base + x - v;
    offsets[c0 + lane] = excl;
    cursor[c0 + lane] = excl;
    base += __shfl(x, 63, 64);
  }
}

__global__ void scatter_k(const int* __restrict__ lab, int* __restrict__ cursor,
                          int* __restrict__ buckets, int n) {
  for (int i = blockIdx.x * 256 + threadIdx.x; i < n; i += gridDim.x * 256) {
    int pos = atomicAdd(&cursor[lab[i]], 1);
    buckets[pos] = i;
  }
}

// per-class sums, 4 blocks per class: atomicAdd partial sums into centers.
// Also accumulates scal[0] = batch sum of x^2 (exact fp32) — each x row is
// visited exactly once across the grid.
__global__ __launch_bounds__(256) void csum_k(const float* __restrict__ x,
    const int* __restrict__ buckets, const int* __restrict__ offsets,
    const int* __restrict__ counts, float* __restrict__ centers,
    float* __restrict__ scal) {
  const int c = blockIdx.x >> 2, q = blockIdx.x & 3;
  const int cnt = counts[c];
  const int t = threadIdx.x;
  float sx = 0.f, sy = 0.f, ssq = 0.f;
  int lo = 0, hi = 0;
  if (cnt) {
    const int beg = offsets[c];
    lo = beg + (cnt * q) / 4;
    hi = beg + (cnt * (q + 1)) / 4;
    for (int i = lo; i < hi; ++i) {
      const int row = buckets[i];
      const float2 v = ((const float2*)(x + (size_t)row * 512))[t];
      sx += v.x;
      sy += v.y;
      ssq += v.x * v.x + v.y * v.y;
    }
    if (lo < hi) {
      atomicAdd(&centers[c * 512 + 2 * t], sx);
      atomicAdd(&centers[c * 512 + 2 * t + 1], sy);
    }
  }
  ssq = waveRed(ssq);
  __shared__ float red[4];
  if ((t & 63) == 0) red[t >> 6] = ssq;
  __syncthreads();
  if (t == 0) {
    const float s = red[0] + red[1] + red[2] + red[3];
    if (s != 0.f) atomicAdd(&scal[0], s);
  }
}

// ||centers[c]||^2 / n_c -> atomic add into out
__global__ __launch_bounds__(256) void cnorm_k(const float* __restrict__ centers,
    const int* __restrict__ counts, float* __restrict__ out) {
  const int c = blockIdx.x;
  const int cnt = counts[c];
  if (cnt == 0) return;
  const float2 v = ((const float2*)(centers + (size_t)c * 512))[threadIdx.x];
  float ssq = v.x * v.x + v.y * v.y;
  ssq = waveRed(ssq);
  __shared__ float red[4];
  if ((threadIdx.x & 63) == 0) red[threadIdx.x >> 6] = ssq;
  __syncthreads();
  if (threadIdx.x == 0)
    atomicAdd(out, (red[0] + red[1] + red[2] + red[3]) / (float)cnt);
}

// vout[row] = badd[row] + sum_k W[row,K] vin[k]; one block per row (fp32 exact)
__global__ __launch_bounds__(256) void matvec_k(const float* __restrict__ W,
    const float* __restrict__ vin, const float* __restrict__ badd,
    float* __restrict__ vout, int K) {
  int row = blockIdx.x;
  float s = 0.f;
  for (int k = threadIdx.x; k < K; k += 256) s += W[(size_t)row * K + k] * vin[k];
  s = waveRed(s);
  __shared__ float red[4];
  if ((threadIdx.x & 63) == 0) red[threadIdx.x >> 6] = s;
  __syncthreads();
  if (threadIdx.x == 0) vout[row] = red[0] + red[1] + red[2] + red[3] + badd[row];
}

// ---------------------------------------------------------------------------
// pk class-sum kernel: sum over batch of the label-column logit, per level.
//   sum_r v_label(r) = sum_c [ dot(S_c, dq(fp8 W_cat[col c])) + n_c*b_c ]
// where S_c = exact fp32 class sums (centers). One wave per (level, class).
// Labels are always < 512 so only the first 512 columns of every level can
// be a label column.
// ---------------------------------------------------------------------------
__global__ void pk_k(const float* __restrict__ centers,
                     const unsigned char* __restrict__ Bcat8,
                     const float* __restrict__ biascat,
                     const int* __restrict__ counts, float* __restrict__ scal) {
  const int b = blockIdx.x;           // [0, 3*512)
  const int lvl = b >> 9;
  const int c = b & 511;
  const int lane = threadIdx.x;       // 64 threads
  const int cbase = (lvl == 0) ? 0 : (lvl == 1) ? 2048 : 3072;
  const float4* S = (const float4*)(centers + (size_t)c * 512);
  const uint2 wb = ((const uint2*)(Bcat8 + (size_t)(cbase + c) * 512))[lane];
  const float4 s0 = S[lane * 2];
  const float4 s1 = S[lane * 2 + 1];
  float s = s0.x * fp8b0(wb.x) + s0.y * fp8b1(wb.x) +
            s0.z * fp8b2(wb.x) + s0.w * fp8b3(wb.x) +
            s1.x * fp8b0(wb.y) + s1.y * fp8b1(wb.y) +
            s1.z * fp8b2(wb.y) + s1.w * fp8b3(wb.y);
  s = waveRed(s);
  if (lane == 0)
    atomicAdd(&scal[5 + lvl], s + (float)counts[c] * biascat[cbase + c]);
}

// ---------------------------------------------------------------------------
// MX-fp8 GEMM for weight collapse: C[M,N] = A[M,K] @ B[N,K]^T, fp8 out
// (row-major C8, optional transposed Ct8). 128x128 tile, BK=128.
// ---------------------------------------------------------------------------
__global__ __launch_bounds__(256) void gemm8_w(
    const unsigned char* __restrict__ A8, const unsigned char* __restrict__ B8,
    int M, int N, int K, unsigned char* __restrict__ C8,
    unsigned char* __restrict__ Ct8) {
  __shared__ __align__(16) unsigned char As[128 * 128];
  __shared__ __align__(16) unsigned char Bs[128 * 128];
  const int tid = threadIdx.x;
  const int lane = tid & 63;
  const int wave = tid >> 6;
  const int lane16 = lane & 15;
  const int quad = lane >> 4;
  const int wm = (wave >> 1) * 64;
  const int wn = (wave & 1) * 64;
  const int m0 = blockIdx.y * 128;
  const int n0 = blockIdx.x * 128;

  f32x4 acc[4][4] = {};

  int srow[4], goff[4];
#pragma unroll
  for (int q = 0; q < 4; ++q) {
    const int s = tid + q * 256;
    const int row = s >> 3;
    const int c16 = s & 7;
    srow[q] = row;
    goff[q] = (((c16 >> 1) ^ (row & 3)) << 5) + ((c16 & 1) << 4);
  }

  for (int kt = 0; kt < K; kt += 128) {
#pragma unroll
    for (int q = 0; q < 4; ++q) {
      const int s = tid + q * 256;
      gload16(A8 + (size_t)(m0 + srow[q]) * K + kt + goff[q], &As[s * 16]);
      gload16(B8 + (size_t)(n0 + srow[q]) * K + kt + goff[q], &Bs[s * 16]);
    }
    __syncthreads();
    i32x8v a8[4], b8[4];
#pragma unroll
    for (int i = 0; i < 4; ++i) {
      const int row = i * 16 + lane16;
      const int sc = quad ^ (row & 3);
      const unsigned char* pa = &As[row * 128 + sc * 32];
      const i32x4v lo = *(const i32x4v*)pa;
      const i32x4v hi = *(const i32x4v*)(pa + 16);
      a8[i] = (i32x8v){lo[0], lo[1], lo[2], lo[3], hi[0], hi[1], hi[2], hi[3]};
    }
#pragma unroll
    for (int j = 0; j < 4; ++j) {
      const int row = j * 16 + lane16;
      const int sc = quad ^ (row & 3);
      const unsigned char* pb = &Bs[row * 128 + sc * 32];
      const i32x4v lo = *(const i32x4v*)pb;
      const i32x4v hi = *(const i32x4v*)(pb + 16);
      b8[j] = (i32x8v){lo[0], lo[1], lo[2], lo[3], hi[0], hi[1], hi[2], hi[3]};
    }
#pragma unroll
    for (int i = 0; i < 4; ++i)
#pragma unroll
      for (int j = 0; j < 4; ++j)
        acc[i][j] = __builtin_amdgcn_mfma_scale_f32_16x16x128_f8f6f4(
            a8[i], b8[j], acc[i][j], 0, 0, 0, 0x7f7f7f7f, 0, 0x7f7f7f7f);
    __syncthreads();
  }
#pragma unroll
  for (int i = 0; i < 4; ++i)
#pragma unroll
    for (int r = 0; r < 4; ++r) {
      const int rowg = m0 + wm + i * 16 + quad * 4 + r;
#pragma unroll
      for (int j = 0; j < 4; ++j) {
        const int colg = n0 + wn + j * 16 + lane16;
        const unsigned char v8 = f2fp8(acc[i][j][r]);
        C8[(size_t)rowg * N + colg] = v8;
        if (Ct8) Ct8[(size_t)colg * M + rowg] = v8;
      }
    }
}

// ---------------------------------------------------------------------------
// reorder: Bcat8 row-major (3584 x 512) -> fragment-major Bp.
// Element (col,k) -> offset (col>>6)*32768 + (k>>7)*8192 + ((col>>4)&3)*2048
//                    + ((((k>>5)&3)*16) + (col&15))*32 + (k&31)
// One thread per 32B k-chunk. Per (tile64, kt): 8KB contiguous; the gemm's
// stream pointer advances linearly 8KB per k-step.
// ---------------------------------------------------------------------------
__global__ void reorder_k(const unsigned char* __restrict__ in,
                          unsigned char* __restrict__ out) {
  const int id = blockIdx.x * 256 + threadIdx.x;   // 57344 chunks
  const int col = id >> 4;
  const int k32 = id & 15;                         // k/32
  const int kt = k32 >> 2, quad = k32 & 3;
  const size_t src = (size_t)col * 512 + k32 * 32;
  const size_t dst = (size_t)(col >> 6) * 32768 + (size_t)kt * 8192 +
                     (size_t)((col >> 4) & 3) * 2048 +
                     (size_t)(quad * 16 + (col & 15)) * 32;
  const uint4 a = *(const uint4*)(in + src);
  const uint4 b = *(const uint4*)(in + src + 16);
  *(uint4*)(out + dst) = a;
  *(uint4*)(out + dst + 16) = b;
}

// ---------------------------------------------------------------------------
// Streaming fused logits+CE GEMM, occupancy-2 variant.
// Block = 256 threads = 4 waves; wave owns 32 rows of x (A in 64 VGPRs).
// Grid = B/128 = 512 blocks -> 2 blocks/CU -> 2 waves/SIMD: cross-wave
// overlap of MFMA vs VALU/loads. B streamed linearly from fragment-major Bp
// with depth-1 register prefetch (explicit ping-pong, no reg rotation).
// Raw s_barrier per tile keeps the 4 waves lock-stepped on the shared B
// stream so L1 serves the intra-block redundancy. No LDS, no waitcnt drains.
// pk (label logit) and sumsq are handled by csum_k/pk_k via the class-sum
// identity -> no per-element label compare in the hot loop.
// ---------------------------------------------------------------------------
__global__ __launch_bounds__(256, 2) void gemm_ce8(
    const float* __restrict__ x, const unsigned char* __restrict__ Bp,
    const float* __restrict__ bias, float* __restrict__ scal) {
  const int tid = threadIdx.x;
  const int lane = tid & 63;
  const int wave = tid >> 6;
  const int lane16 = lane & 15;
  const int quad = lane >> 4;
  const int m0 = blockIdx.x * 128 + wave * 32;

  // ---- A: 32 rows x 512 fp8 in VGPRs, fused fp32->fp8 ----
  i32x8v a[2][4];
#pragma unroll
  for (int i = 0; i < 2; ++i) {
    const float* xr = x + (size_t)(m0 + i * 16 + lane16) * 512 + quad * 32;
#pragma unroll
    for (int kt = 0; kt < 4; ++kt) {
      const float4* p4 = (const float4*)(xr + kt * 128);
      int d[8];
#pragma unroll
      for (int p = 0; p < 8; ++p) {
        const float4 f = p4[p];
        int w_ = __builtin_amdgcn_cvt_pk_fp8_f32(f.x, f.y, 0, false);
        w_ = __builtin_amdgcn_cvt_pk_fp8_f32(f.z, f.w, w_, true);
        d[p] = w_;
      }
      a[i][kt] = (i32x8v){d[0], d[1], d[2], d[3], d[4], d[5], d[6], d[7]};
    }
  }

  // ---- B stream: linear, depth-1 prefetch, ping-pong buffers ----
  const unsigned char* bp = Bp + lane * 32;
  i32x8v bc[4], bn[4];
#pragma unroll
  for (int j = 0; j < 4; ++j) bc[j] = *(const i32x8v*)(bp + j * 2048);
  bp += 8192;

  float es[8];
#pragma unroll
  for (int k = 0; k < 8; ++k) es[k] = 0.f;

  int tile = 0;
#pragma unroll 1
  for (int lvl = 0; lvl < 3; ++lvl) {
    const int nt = (lvl == 0) ? 32 : (lvl == 1) ? 16 : 8;
#pragma unroll 1
    for (int t = 0; t < nt; ++t, ++tile) {
      f32x4 acc[2][4] = {};
#pragma unroll
      for (int kt2 = 0; kt2 < 2; ++kt2) {
        // even k-step: consume bc, load into bn
#pragma unroll
        for (int j = 0; j < 4; ++j) bn[j] = *(const i32x8v*)(bp + j * 2048);
        bp += 8192;
#pragma unroll
        for (int i = 0; i < 2; ++i)
#pragma unroll
          for (int j = 0; j < 4; ++j)
            acc[i][j] = __builtin_amdgcn_mfma_scale_f32_16x16x128_f8f6f4(
                a[i][kt2 * 2], bc[j], acc[i][j], 0, 0, 0, 0x7f7f7f7f, 0,
                0x7f7f7f7f);
        // odd k-step: consume bn, load into bc
#pragma unroll
        for (int j = 0; j < 4; ++j) bc[j] = *(const i32x8v*)(bp + j * 2048);
        bp += 8192;
#pragma unroll
        for (int i = 0; i < 2; ++i)
#pragma unroll
          for (int j = 0; j < 4; ++j)
            acc[i][j] = __builtin_amdgcn_mfma_scale_f32_16x16x128_f8f6f4(
                a[i][kt2 * 2 + 1], bn[j], acc[i][j], 0, 0, 0, 0x7f7f7f7f, 0,
                0x7f7f7f7f);
      }
      // ---- register CE epilogue (sum of exp only; pk handled by pk_k) ----
      float bj[4];
#pragma unroll
      for (int j = 0; j < 4; ++j) bj[j] = bias[tile * 64 + j * 16 + lane16];
#pragma unroll
      for (int i = 0; i < 2; ++i)
#pragma unroll
        for (int r = 0; r < 4; ++r) {
          float e = 0.f;
#pragma unroll
          for (int j = 0; j < 4; ++j) e += __expf(acc[i][j][r] + bj[j]);
          es[i * 4 + r] += e;
        }
      // keep the block's 4 waves lock-stepped on the shared B stream (L1 reuse)
      __builtin_amdgcn_s_barrier();
    }
    // ---- level close: reduce es over lane16, log, accumulate ----
    float ls = 0.f;
#pragma unroll
    for (int k = 0; k < 8; ++k) {
      float tot = es[k];
      tot += __shfl_xor(tot, 1, 64);
      tot += __shfl_xor(tot, 2, 64);
      tot += __shfl_xor(tot, 4, 64);
      tot += __shfl_xor(tot, 8, 64);
      if (lane16 == 0) ls += __logf(tot);
      es[k] = 0.f;
    }
    ls = waveRed(ls);
    if (lane == 0) atomicAdd(&scal[2 + lvl], ls);
  }
}

// scal: [0]=sumsq_x [1]=sum ||sums_c||^2/n_c [2..4]=logsumexp sums [5..7]=pk sums
__global__ void fin_k(const float* __restrict__ scal, const float* __restrict__ lam,
                      float* __restrict__ out, float invB) {
  if (threadIdx.x == 0 && blockIdx.x == 0)
    out[0] = lam[0] * (scal[0] - scal[1]) +
             (lam[1] * (scal[2] - scal[5]) + lam[2] * (scal[3] - scal[6]) +
              lam[3] * (scal[4] - scal[7])) * invB;
}

// ---------------------------------------------------------------------------
// Launch
// ---------------------------------------------------------------------------
extern "C" void kernel_launch(void* const* d_in, const int* in_sizes, int n_in,
                              void* d_out, int out_size, void* d_ws, size_t ws_size,
                              hipStream_t stream) {
  const float* x   = (const float*)d_in[0];
  const float* W0  = (const float*)d_in[1];
  const float* b0  = (const float*)d_in[2];
  const float* W1  = (const float*)d_in[3];
  const float* b1  = (const float*)d_in[4];
  const float* W2  = (const float*)d_in[5];
  const float* b2  = (const float*)d_in[6];
  const float* lam = (const float*)d_in[7];
  const int*   lab = (const int*)d_in[8];

  const int Bsz = in_sizes[8];         // 65536
  const int D   = in_sizes[0] / Bsz;   // 512
  const int N0  = in_sizes[2];         // 2048
  const int N1  = in_sizes[4];         // 1024
  const int N2  = in_sizes[6];         // 512
  const int Ncat = N0 + N1 + N2;       // 3584
  const int NCLS = 512;

  char* w = (char*)d_ws;
  size_t off = 0;
  auto alloc = [&](size_t bytes) -> void* {
    void* p = w + off;
    off += (bytes + 255) & ~(size_t)255;
    return p;
  };

  unsigned char* Bcat8 = (unsigned char*)alloc((size_t)Ncat * D);         // row-major
  unsigned char* Bp    = (unsigned char*)alloc((size_t)Ncat * D + 16384); // frag-major (+slack)
  unsigned char* W1_8  = (unsigned char*)alloc((size_t)N1 * N0);
  unsigned char* W2_8  = (unsigned char*)alloc((size_t)N2 * N1);
  unsigned char* W0t8  = (unsigned char*)alloc((size_t)D * N0);
  unsigned char* M1t8  = (unsigned char*)alloc((size_t)D * N1);
  float* biascat = (float*)alloc((size_t)Ncat * 4);
  int* offsets = (int*)alloc(NCLS * 4);
  int* cursor  = (int*)alloc(NCLS * 4);
  int* buckets = (int*)alloc((size_t)Bsz * 4);
  // zero region: counts(512i) | scal(8f) | centers(512*512f)
  const int zwords = NCLS + 8 + NCLS * 512;
  char* zr = (char*)alloc((size_t)zwords * 4);
  int*   counts  = (int*)zr;
  float* scal    = (float*)(zr + NCLS * 4);
  float* centers = (float*)(zr + NCLS * 4 + 32);
  (void)ws_size; (void)n_in; (void)out_size;

  // fused prep: weight fp8 conversions + W0^T + zero + b0 copy
  const int zb = (zwords + 255) / 256;
  prep_w<<<dim3(1792 + zb + 8), dim3(256), 0, stream>>>(
      (const float4*)W1, (const float4*)W2, (const float4*)W0, W0, b0,
      (uint32_t*)W1_8, (uint32_t*)W2_8, (uint32_t*)Bcat8, W0t8,
      (float*)zr, zwords, biascat);

  // center-loss bucketing + class sums (fp32-exact) + batch sumsq
  count_k<<<dim3(32), dim3(256), 0, stream>>>(lab, counts, Bsz);
  prefix_k<<<dim3(1), dim3(64), 0, stream>>>(counts, offsets, cursor, NCLS);
  scatter_k<<<dim3(256), dim3(256), 0, stream>>>(lab, cursor, buckets, Bsz);
  csum_k<<<dim3(4 * NCLS), dim3(256), 0, stream>>>(x, buckets, offsets, counts,
                                                   centers, scal);
  cnorm_k<<<dim3(NCLS), dim3(256), 0, stream>>>(centers, counts, &scal[1]);

  // collapsed biases: biascat = [b0 | b1 + W1 b0 | b2 + W2 c1] (fp32 exact)
  matvec_k<<<dim3(N1), dim3(256), 0, stream>>>(W1, b0, b1, biascat + N0, N0);
  matvec_k<<<dim3(N2), dim3(256), 0, stream>>>(W2, biascat + N0, b2, biascat + N0 + N1, N1);

  // collapsed weights (fp8): M1 = W1@W0 -> Bcat8 seg1 + M1t8; M2 = W2@M1 -> seg2
  gemm8_w<<<dim3(D / 128, N1 / 128), dim3(256), 0, stream>>>(
      W1_8, W0t8, N1, D, N0, Bcat8 + (size_t)N0 * D, M1t8);
  gemm8_w<<<dim3(D / 128, N2 / 128), dim3(256), 0, stream>>>(
      W2_8, M1t8, N2, D, N1, Bcat8 + (size_t)(N0 + N1) * D, nullptr);

  // row-major -> fragment-major
  reorder_k<<<dim3(Ncat * D / 32 / 256), dim3(256), 0, stream>>>(Bcat8, Bp);

  // pk via class-sum identity (needs Bcat8 complete + centers + biascat + counts)
  pk_k<<<dim3(3 * NCLS), dim3(64), 0, stream>>>(centers, Bcat8, biascat,
                                                counts, scal);

  // streaming fused logits+CE (all three levels), 2 blocks/CU
  gemm_ce8<<<dim3(Bsz / 128), dim3(256), 0, stream>>>(x, Bp, biascat, scal);

  fin_k<<<dim3(1), dim3(64), 0, stream>>>(scal, lam, (float*)d_out, 1.f / (float)Bsz);
}

// Round 3
// 517.201 us; speedup vs baseline: 1.0435x; 1.0435x over previous
//
#include <hip/hip_runtime.h>
#include <cstdint>
#include <cstddef>

// ---------------------------------------------------------------------------
// Types / helpers
// ---------------------------------------------------------------------------
using f32x4  = __attribute__((ext_vector_type(4))) float;
using i32x4v = __attribute__((ext_vector_type(4))) int;
using i32x8v = __attribute__((ext_vector_type(8))) int;

__device__ __forceinline__ unsigned char f2fp8(float f) {
  return (unsigned char)(__builtin_amdgcn_cvt_pk_fp8_f32(f, f, 0, false) & 0xff);
}

// exact dequant of OCP e4m3fn byte (sel selects byte of w)
__device__ __forceinline__ float fp8b0(unsigned int w) {
  return __builtin_amdgcn_cvt_f32_fp8(w, 0);
}
__device__ __forceinline__ float fp8b1(unsigned int w) {
  return __builtin_amdgcn_cvt_f32_fp8(w, 1);
}
__device__ __forceinline__ float fp8b2(unsigned int w) {
  return __builtin_amdgcn_cvt_f32_fp8(w, 2);
}
__device__ __forceinline__ float fp8b3(unsigned int w) {
  return __builtin_amdgcn_cvt_f32_fp8(w, 3);
}

__device__ __forceinline__ float waveRed(float v) {
#pragma unroll
  for (int m = 32; m >= 1; m >>= 1) v += __shfl_xor(v, m, 64);
  return v;
}

// async global->LDS, 16B per lane. LDS dest must be wave-uniform base + lane*16.
__device__ __forceinline__ void gload16(const void* g, void* l) {
  __builtin_amdgcn_global_load_lds(
      (__attribute__((address_space(1))) uint32_t*)(uintptr_t)g,
      (__attribute__((address_space(3))) uint32_t*)(uint32_t*)l,
      16, 0, 0);
}

// ---------------------------------------------------------------------------
// prep_w: fused weight prep + workspace zeroing + b0 copy.
// blocks [0,1024)    : W1 -> fp8
// blocks [1024,1280) : W2 -> fp8
// blocks [1280,1536) : W0 -> fp8 row-major (Bcat8 seg0)
// blocks [1536,1792) : W0^T -> fp8 (LDS-tiled)
// blocks [1792,1792+zb) : zero zr region (zwords)
// blocks [1792+zb, +8)  : biascat[0..2047] = b0
// ---------------------------------------------------------------------------
__global__ __launch_bounds__(256) void prep_w(
    const float4* __restrict__ W1, const float4* __restrict__ W2,
    const float4* __restrict__ W0f4, const float* __restrict__ W0,
    const float* __restrict__ b0,
    uint32_t* __restrict__ W1_8, uint32_t* __restrict__ W2_8,
    uint32_t* __restrict__ W0_8, unsigned char* __restrict__ W0t8,
    float* __restrict__ zr, int zwords, float* __restrict__ biascat) {
  __shared__ unsigned char t8[64][65];
  const int b = blockIdx.x;
  const int tid = threadIdx.x;
  if (b < 1024) {
    for (int i = b * 256 + tid; i < 524288; i += 1024 * 256) {
      float4 v = W1[i];
      int p = __builtin_amdgcn_cvt_pk_fp8_f32(v.x, v.y, 0, false);
      p = __builtin_amdgcn_cvt_pk_fp8_f32(v.z, v.w, p, true);
      W1_8[i] = (uint32_t)p;
    }
  } else if (b < 1280) {
    for (int i = (b - 1024) * 256 + tid; i < 131072; i += 256 * 256) {
      float4 v = W2[i];
      int p = __builtin_amdgcn_cvt_pk_fp8_f32(v.x, v.y, 0, false);
      p = __builtin_amdgcn_cvt_pk_fp8_f32(v.z, v.w, p, true);
      W2_8[i] = (uint32_t)p;
    }
  } else if (b < 1536) {
    for (int i = (b - 1280) * 256 + tid; i < 262144; i += 256 * 256) {
      float4 v = W0f4[i];
      int p = __builtin_amdgcn_cvt_pk_fp8_f32(v.x, v.y, 0, false);
      p = __builtin_amdgcn_cvt_pk_fp8_f32(v.z, v.w, p, true);
      W0_8[i] = (uint32_t)p;
    }
  } else if (b < 1792) {
    // transpose W0 (2048 x 512 fp32) -> W0t8 (512 x 2048 fp8)
    const int t = b - 1536;             // 32 row-tiles x 8 col-tiles
    const int r0 = (t >> 3) * 64, c0 = (t & 7) * 64;
#pragma unroll
    for (int p = 0; p < 16; ++p) {
      const int row = p * 4 + (tid >> 6), col = tid & 63;
      t8[row][col] = f2fp8(W0[(size_t)(r0 + row) * 512 + c0 + col]);
    }
    __syncthreads();
#pragma unroll
    for (int p = 0; p < 16; ++p) {
      const int oc = p * 4 + (tid >> 6), orr = tid & 63;
      W0t8[(size_t)(c0 + oc) * 2048 + r0 + orr] = t8[orr][oc];
    }
  } else {
    const int zb = (zwords + 255) >> 8;
    if (b < 1792 + zb) {
      const int i = (b - 1792) * 256 + tid;
      if (i < zwords) zr[i] = 0.f;
    } else {
      const int i = (b - 1792 - zb) * 256 + tid;
      if (i < 2048) biascat[i] = b0[i];
    }
  }
}

// LDS-histogram label count
__global__ __launch_bounds__(256) void count_k(const int* __restrict__ lab,
                                               int* __restrict__ counts, int n) {
  __shared__ int h[512];
  for (int i = threadIdx.x; i < 512; i += 256) h[i] = 0;
  __syncthreads();
  for (int i = blockIdx.x * 256 + threadIdx.x; i < n; i += gridDim.x * 256)
    atomicAdd(&h[lab[i]], 1);
  __syncthreads();
  for (int i = threadIdx.x; i < 512; i += 256) {
    int v = h[i];
    if (v) atomicAdd(&counts[i], v);
  }
}

// single-wave shuffle scan
__global__ void prefix_k(const int* __restrict__ counts, int* __restrict__ offsets,
                         int* __restrict__ cursor, int nc) {
  const int lane = threadIdx.x;  // 64 threads
  int base = 0;
  for (int c0 = 0; c0 < nc; c0 += 64) {
    int v = counts[c0 + lane];
    int x = v;
#pragma unroll
    for (int d = 1; d < 64; d <<= 1) {
      int y = __shfl_up(x, d, 64);
      if (lane >= d) x += y;
    }
    int excl = base + x - v;
    offsets[c0 + lane] = excl;
    cursor[c0 + lane] = excl;
    base += __shfl(x, 63, 64);
  }
}

__global__ void scatter_k(const int* __restrict__ lab, int* __restrict__ cursor,
                          int* __restrict__ buckets, int n) {
  for (int i = blockIdx.x * 256 + threadIdx.x; i < n; i += gridDim.x * 256) {
    int pos = atomicAdd(&cursor[lab[i]], 1);
    buckets[pos] = i;
  }
}

// per-class sums, 4 blocks per class -> PLAIN stores of partials (no atomics).
// centers4[(c*4+q)*512 + d]; written unconditionally (zeros if range empty),
// so centers4 needs no pre-zeroing. Also scal[0] += batch sum of x^2.
__global__ __launch_bounds__(256) void csum_k(const float* __restrict__ x,
    const int* __restrict__ buckets, const int* __restrict__ offsets,
    const int* __restrict__ counts, float* __restrict__ centers4,
    float* __restrict__ scal) {
  const int c = blockIdx.x >> 2, q = blockIdx.x & 3;
  const int cnt = counts[c];
  const int t = threadIdx.x;
  float sx = 0.f, sy = 0.f, ssq = 0.f;
  if (cnt) {
    const int beg = offsets[c];
    const int lo = beg + (cnt * q) / 4, hi = beg + (cnt * (q + 1)) / 4;
    for (int i = lo; i < hi; ++i) {
      const int row = buckets[i];
      const float2 v = ((const float2*)(x + (size_t)row * 512))[t];
      sx += v.x;
      sy += v.y;
      ssq += v.x * v.x + v.y * v.y;
    }
  }
  float2* dst = (float2*)(centers4 + (size_t)((c << 2) + q) * 512);
  dst[t] = make_float2(sx, sy);
  ssq = waveRed(ssq);
  __shared__ float red[4];
  if ((t & 63) == 0) red[t >> 6] = ssq;
  __syncthreads();
  if (t == 0) {
    const float s = red[0] + red[1] + red[2] + red[3];
    if (s != 0.f) atomicAdd(&scal[0], s);
  }
}

// sum the 4 partials -> centers[c] (for pk_k), plus ||S_c||^2/n_c -> out.
__global__ __launch_bounds__(256) void cnorm_k(const float* __restrict__ centers4,
    float* __restrict__ centers, const int* __restrict__ counts,
    float* __restrict__ out) {
  const int c = blockIdx.x;
  const int t = threadIdx.x;
  const float2* p = (const float2*)(centers4 + (size_t)(c << 2) * 512);
  float2 s = p[t];
  float2 s1 = p[t + 256], s2 = p[t + 512], s3 = p[t + 768];
  s.x += s1.x + s2.x + s3.x;
  s.y += s1.y + s2.y + s3.y;
  ((float2*)(centers + (size_t)c * 512))[t] = s;
  const int cnt = counts[c];
  if (cnt == 0) return;
  float ssq = s.x * s.x + s.y * s.y;
  ssq = waveRed(ssq);
  __shared__ float red[4];
  if ((t & 63) == 0) red[t >> 6] = ssq;
  __syncthreads();
  if (t == 0)
    atomicAdd(out, (red[0] + red[1] + red[2] + red[3]) / (float)cnt);
}

// vout[row] = badd[row] + sum_k W[row,K] vin[k]; one block per row (fp32 exact)
__global__ __launch_bounds__(256) void matvec_k(const float* __restrict__ W,
    const float* __restrict__ vin, const float* __restrict__ badd,
    float* __restrict__ vout, int K) {
  int row = blockIdx.x;
  float s = 0.f;
  for (int k = threadIdx.x; k < K; k += 256) s += W[(size_t)row * K + k] * vin[k];
  s = waveRed(s);
  __shared__ float red[4];
  if ((threadIdx.x & 63) == 0) red[threadIdx.x >> 6] = s;
  __syncthreads();
  if (threadIdx.x == 0) vout[row] = red[0] + red[1] + red[2] + red[3] + badd[row];
}

// ---------------------------------------------------------------------------
// pk class-sum kernel: sum over batch of the label-column logit, per level.
//   sum_r v_label(r) = sum_c [ dot(S_c, dq(fp8 W_cat[col c])) + n_c*b_c ]
// where S_c = exact fp32 class sums (centers). One wave per (level, class).
// ---------------------------------------------------------------------------
__global__ void pk_k(const float* __restrict__ centers,
                     const unsigned char* __restrict__ Bcat8,
                     const float* __restrict__ biascat,
                     const int* __restrict__ counts, float* __restrict__ scal) {
  const int b = blockIdx.x;           // [0, 3*512)
  const int lvl = b >> 9;
  const int c = b & 511;
  const int lane = threadIdx.x;       // 64 threads
  const int cbase = (lvl == 0) ? 0 : (lvl == 1) ? 2048 : 3072;
  const float4* S = (const float4*)(centers + (size_t)c * 512);
  const uint2 wb = ((const uint2*)(Bcat8 + (size_t)(cbase + c) * 512))[lane];
  const float4 s0 = S[lane * 2];
  const float4 s1 = S[lane * 2 + 1];
  float s = s0.x * fp8b0(wb.x) + s0.y * fp8b1(wb.x) +
            s0.z * fp8b2(wb.x) + s0.w * fp8b3(wb.x) +
            s1.x * fp8b0(wb.y) + s1.y * fp8b1(wb.y) +
            s1.z * fp8b2(wb.y) + s1.w * fp8b3(wb.y);
  s = waveRed(s);
  if (lane == 0)
    atomicAdd(&scal[5 + lvl], s + (float)counts[c] * biascat[cbase + c]);
}

// ---------------------------------------------------------------------------
// MX-fp8 GEMM for weight collapse: C[M,N] = A[M,K] @ B[N,K]^T, fp8 out
// (row-major C8, optional transposed Ct8). 128x128 tile, BK=128.
// ---------------------------------------------------------------------------
__global__ __launch_bounds__(256) void gemm8_w(
    const unsigned char* __restrict__ A8, const unsigned char* __restrict__ B8,
    int M, int N, int K, unsigned char* __restrict__ C8,
    unsigned char* __restrict__ Ct8) {
  __shared__ __align__(16) unsigned char As[128 * 128];
  __shared__ __align__(16) unsigned char Bs[128 * 128];
  const int tid = threadIdx.x;
  const int lane = tid & 63;
  const int wave = tid >> 6;
  const int lane16 = lane & 15;
  const int quad = lane >> 4;
  const int wm = (wave >> 1) * 64;
  const int wn = (wave & 1) * 64;
  const int m0 = blockIdx.y * 128;
  const int n0 = blockIdx.x * 128;

  f32x4 acc[4][4] = {};

  int srow[4], goff[4];
#pragma unroll
  for (int q = 0; q < 4; ++q) {
    const int s = tid + q * 256;
    const int row = s >> 3;
    const int c16 = s & 7;
    srow[q] = row;
    goff[q] = (((c16 >> 1) ^ (row & 3)) << 5) + ((c16 & 1) << 4);
  }

  for (int kt = 0; kt < K; kt += 128) {
#pragma unroll
    for (int q = 0; q < 4; ++q) {
      const int s = tid + q * 256;
      gload16(A8 + (size_t)(m0 + srow[q]) * K + kt + goff[q], &As[s * 16]);
      gload16(B8 + (size_t)(n0 + srow[q]) * K + kt + goff[q], &Bs[s * 16]);
    }
    __syncthreads();
    i32x8v a8[4], b8[4];
#pragma unroll
    for (int i = 0; i < 4; ++i) {
      const int row = i * 16 + lane16;
      const int sc = quad ^ (row & 3);
      const unsigned char* pa = &As[row * 128 + sc * 32];
      const i32x4v lo = *(const i32x4v*)pa;
      const i32x4v hi = *(const i32x4v*)(pa + 16);
      a8[i] = (i32x8v){lo[0], lo[1], lo[2], lo[3], hi[0], hi[1], hi[2], hi[3]};
    }
#pragma unroll
    for (int j = 0; j < 4; ++j) {
      const int row = j * 16 + lane16;
      const int sc = quad ^ (row & 3);
      const unsigned char* pb = &Bs[row * 128 + sc * 32];
      const i32x4v lo = *(const i32x4v*)pb;
      const i32x4v hi = *(const i32x4v*)(pb + 16);
      b8[j] = (i32x8v){lo[0], lo[1], lo[2], lo[3], hi[0], hi[1], hi[2], hi[3]};
    }
#pragma unroll
    for (int i = 0; i < 4; ++i)
#pragma unroll
      for (int j = 0; j < 4; ++j)
        acc[i][j] = __builtin_amdgcn_mfma_scale_f32_16x16x128_f8f6f4(
            a8[i], b8[j], acc[i][j], 0, 0, 0, 0x7f7f7f7f, 0, 0x7f7f7f7f);
    __syncthreads();
  }
#pragma unroll
  for (int i = 0; i < 4; ++i)
#pragma unroll
    for (int r = 0; r < 4; ++r) {
      const int rowg = m0 + wm + i * 16 + quad * 4 + r;
#pragma unroll
      for (int j = 0; j < 4; ++j) {
        const int colg = n0 + wn + j * 16 + lane16;
        const unsigned char v8 = f2fp8(acc[i][j][r]);
        C8[(size_t)rowg * N + colg] = v8;
        if (Ct8) Ct8[(size_t)colg * M + rowg] = v8;
      }
    }
}

// ---------------------------------------------------------------------------
// reorder: Bcat8 row-major (3584 x 512) -> fragment-major Bp, LDS-friendly.
// Chunk g = tile64*4 + kt is 8KB contiguous. Within a chunk, fragment j
// occupies [j*2048, j*2048+2048). Within a fragment, lane l's 32B k-window
// is SPLIT: k-bytes 0-15 at l*16, k-bytes 16-31 at 1024 + l*16, so the
// gemm's two ds_read_b128 per fragment are lane-consecutive (conflict-free).
// lane l = ((k>>5)&3)*16 + (col&15).
// ---------------------------------------------------------------------------
__global__ void reorder_k(const unsigned char* __restrict__ in,
                          unsigned char* __restrict__ out) {
  const int id = blockIdx.x * 256 + threadIdx.x;   // 57344 chunks
  const int col = id >> 4;
  const int k32 = id & 15;                         // k/32
  const int kt = k32 >> 2, quad = k32 & 3;
  const int l = quad * 16 + (col & 15);
  const size_t src = (size_t)col * 512 + k32 * 32;
  const size_t fragbase = (size_t)(col >> 6) * 32768 + (size_t)kt * 8192 +
                          (size_t)((col >> 4) & 3) * 2048;
  const uint4 a = *(const uint4*)(in + src);        // k-bytes 0-15
  const uint4 b = *(const uint4*)(in + src + 16);   // k-bytes 16-31
  *(uint4*)(out + fragbase + l * 16) = a;
  *(uint4*)(out + fragbase + 1024 + l * 16) = b;
}

// ---------------------------------------------------------------------------
// Streaming fused logits+CE GEMM, LDS-shared B variant.
// Block = 256 threads = 4 waves; wave owns 32 rows of x (A in 64 VGPRs).
// Grid = B/128 = 512 blocks -> 2 blocks/CU -> 2 waves/SIMD.
// B: each 8KB k-step chunk is staged into a 4-deep LDS ring ONCE per block
// (cooperative global_load_lds, wave w stages bytes [w*2KB,(w+1)*2KB)), then
// all 4 waves ds_read their fragments. This cuts per-CU VMEM traffic 4x
// (14.7MB -> 3.7MB) off the saturated L1/L2 path; the 8x reuse moves to LDS
// (128B/cyc). Ring discipline: per k-step { issue next chunk, vmcnt(2),
// s_barrier, ds_read, MFMA }. Barrier bounds wave skew <1 step; 4 slots make
// writer(slot g+2 at worst) vs reader(slot g) disjoint. Bias lives in LDS so
// the loop's VMEM queue holds only counted gloads.
// ---------------------------------------------------------------------------
__global__ __launch_bounds__(256, 2) void gemm_ce8(
    const float* __restrict__ x, const unsigned char* __restrict__ Bp,
    const float* __restrict__ bias, float* __restrict__ scal) {
  __shared__ __align__(16) unsigned char Bl[4][8192];
  __shared__ float biasl[3584];
  const int tid = threadIdx.x;
  const int lane = tid & 63;
  const int wave = tid >> 6;
  const int lane16 = lane & 15;
  const int quad = lane >> 4;
  const int m0 = blockIdx.x * 128 + wave * 32;

  // ---- bias -> LDS (once) ----
  for (int i = tid; i < 3584; i += 256) biasl[i] = bias[i];

  // ---- A: 32 rows x 512 fp8 in VGPRs, fused fp32->fp8 ----
  i32x8v a[2][4];
#pragma unroll
  for (int i = 0; i < 2; ++i) {
    const float* xr = x + (size_t)(m0 + i * 16 + lane16) * 512 + quad * 32;
#pragma unroll
    for (int kt = 0; kt < 4; ++kt) {
      const float4* p4 = (const float4*)(xr + kt * 128);
      int d[8];
#pragma unroll
      for (int p = 0; p < 8; ++p) {
        const float4 f = p4[p];
        int w_ = __builtin_amdgcn_cvt_pk_fp8_f32(f.x, f.y, 0, false);
        w_ = __builtin_amdgcn_cvt_pk_fp8_f32(f.z, f.w, w_, true);
        d[p] = w_;
      }
      a[i][kt] = (i32x8v){d[0], d[1], d[2], d[3], d[4], d[5], d[6], d[7]};
    }
  }
  __syncthreads();  // biasl visible; VMEM queue drained (all x loads consumed)

  // ---- B ring: prologue stage of chunk 0 into slot 0 ----
  const int soff = wave * 2048 + lane * 16;
  gload16(Bp + soff, &Bl[0][soff]);
  gload16(Bp + soff + 1024, &Bl[0][soff + 1024]);
  const unsigned char* bsrc = Bp + soff + 8192;  // source for chunk g+1

  float es[8];
#pragma unroll
  for (int k = 0; k < 8; ++k) es[k] = 0.f;

  int tile = 0;
#pragma unroll 1
  for (int lvl = 0; lvl < 3; ++lvl) {
    const int nt = (lvl == 0) ? 32 : (lvl == 1) ? 16 : 8;
#pragma unroll 1
    for (int t = 0; t < nt; ++t, ++tile) {
      f32x4 acc[2][4] = {};
#pragma unroll
      for (int ks = 0; ks < 4; ++ks) {
        // stage chunk g+1 into slot (ks+1)&3 (tile*4 ≡ 0 mod 4 -> slot = ks)
        const int nslot = (ks + 1) & 3;
        gload16(bsrc, &Bl[nslot][soff]);
        gload16(bsrc + 1024, &Bl[nslot][soff + 1024]);
        bsrc += 8192;
        // own chunk-g loads done (2 newest outstanding are chunk g+1)
        asm volatile("s_waitcnt vmcnt(2)" ::: "memory");
        asm volatile("s_barrier" ::: "memory");
        const unsigned char* bb = &Bl[ks][0];
        i32x8v b8[4];
#pragma unroll
        for (int j = 0; j < 4; ++j) {
          const i32x4v lo = *(const i32x4v*)(bb + j * 2048 + lane * 16);
          const i32x4v hi = *(const i32x4v*)(bb + j * 2048 + 1024 + lane * 16);
          b8[j] = (i32x8v){lo[0], lo[1], lo[2], lo[3],
                           hi[0], hi[1], hi[2], hi[3]};
        }
#pragma unroll
        for (int i = 0; i < 2; ++i)
#pragma unroll
          for (int j = 0; j < 4; ++j)
            acc[i][j] = __builtin_amdgcn_mfma_scale_f32_16x16x128_f8f6f4(
                a[i][ks], b8[j], acc[i][j], 0, 0, 0, 0x7f7f7f7f, 0,
                0x7f7f7f7f);
      }
      // ---- register CE epilogue (bias from LDS; pk handled by pk_k) ----
      float bj[4];
#pragma unroll
      for (int j = 0; j < 4; ++j) bj[j] = biasl[tile * 64 + j * 16 + lane16];
#pragma unroll
      for (int i = 0; i < 2; ++i)
#pragma unroll
        for (int r = 0; r < 4; ++r) {
          float e = 0.f;
#pragma unroll
          for (int j = 0; j < 4; ++j) e += __expf(acc[i][j][r] + bj[j]);
          es[i * 4 + r] += e;
        }
    }
    // ---- level close: reduce es over lane16, log, accumulate ----
    float ls = 0.f;
#pragma unroll
    for (int k = 0; k < 8; ++k) {
      float tot = es[k];
      tot += __shfl_xor(tot, 1, 64);
      tot += __shfl_xor(tot, 2, 64);
      tot += __shfl_xor(tot, 4, 64);
      tot += __shfl_xor(tot, 8, 64);
      if (lane16 == 0) ls += __logf(tot);
      es[k] = 0.f;
    }
    ls = waveRed(ls);
    if (lane == 0) atomicAdd(&scal[2 + lvl], ls);
  }
}

// scal: [0]=sumsq_x [1]=sum ||sums_c||^2/n_c [2..4]=logsumexp sums [5..7]=pk sums
__global__ void fin_k(const float* __restrict__ scal, const float* __restrict__ lam,
                      float* __restrict__ out, float invB) {
  if (threadIdx.x == 0 && blockIdx.x == 0)
    out[0] = lam[0] * (scal[0] - scal[1]) +
             (lam[1] * (scal[2] - scal[5]) + lam[2] * (scal[3] - scal[6]) +
              lam[3] * (scal[4] - scal[7])) * invB;
}

// ---------------------------------------------------------------------------
// Launch
// ---------------------------------------------------------------------------
extern "C" void kernel_launch(void* const* d_in, const int* in_sizes, int n_in,
                              void* d_out, int out_size, void* d_ws, size_t ws_size,
                              hipStream_t stream) {
  const float* x   = (const float*)d_in[0];
  const float* W0  = (const float*)d_in[1];
  const float* b0  = (const float*)d_in[2];
  const float* W1  = (const float*)d_in[3];
  const float* b1  = (const float*)d_in[4];
  const float* W2  = (const float*)d_in[5];
  const float* b2  = (const float*)d_in[6];
  const float* lam = (const float*)d_in[7];
  const int*   lab = (const int*)d_in[8];

  const int Bsz = in_sizes[8];         // 65536
  const int D   = in_sizes[0] / Bsz;   // 512
  const int N0  = in_sizes[2];         // 2048
  const int N1  = in_sizes[4];         // 1024
  const int N2  = in_sizes[6];         // 512
  const int Ncat = N0 + N1 + N2;       // 3584
  const int NCLS = 512;

  char* w = (char*)d_ws;
  size_t off = 0;
  auto alloc = [&](size_t bytes) -> void* {
    void* p = w + off;
    off += (bytes + 255) & ~(size_t)255;
    return p;
  };

  unsigned char* Bcat8 = (unsigned char*)alloc((size_t)Ncat * D);         // row-major
  unsigned char* Bp    = (unsigned char*)alloc((size_t)Ncat * D + 16384); // frag-major (+slack)
  unsigned char* W1_8  = (unsigned char*)alloc((size_t)N1 * N0);
  unsigned char* W2_8  = (unsigned char*)alloc((size_t)N2 * N1);
  unsigned char* W0t8  = (unsigned char*)alloc((size_t)D * N0);
  unsigned char* M1t8  = (unsigned char*)alloc((size_t)D * N1);
  float* biascat  = (float*)alloc((size_t)Ncat * 4);
  int* offsets = (int*)alloc(NCLS * 4);
  int* cursor  = (int*)alloc(NCLS * 4);
  int* buckets = (int*)alloc((size_t)Bsz * 4);
  float* centers4 = (float*)alloc((size_t)NCLS * 512 * 4 * 4);  // partials (no zero)
  float* centers  = (float*)alloc((size_t)NCLS * 512 * 4);      // summed (no zero)
  // zero region: counts(512i) | scal(8f)
  const int zwords = NCLS + 8;
  char* zr = (char*)alloc((size_t)zwords * 4);
  int*   counts  = (int*)zr;
  float* scal    = (float*)(zr + NCLS * 4);
  (void)ws_size; (void)n_in; (void)out_size;

  // fused prep: weight fp8 conversions + W0^T + zero + b0 copy
  const int zb = (zwords + 255) / 256;
  prep_w<<<dim3(1792 + zb + 8), dim3(256), 0, stream>>>(
      (const float4*)W1, (const float4*)W2, (const float4*)W0, W0, b0,
      (uint32_t*)W1_8, (uint32_t*)W2_8, (uint32_t*)Bcat8, W0t8,
      (float*)zr, zwords, biascat);

  // center-loss bucketing + class partial sums (plain stores) + batch sumsq
  count_k<<<dim3(32), dim3(256), 0, stream>>>(lab, counts, Bsz);
  prefix_k<<<dim3(1), dim3(64), 0, stream>>>(counts, offsets, cursor, NCLS);
  scatter_k<<<dim3(256), dim3(256), 0, stream>>>(lab, cursor, buckets, Bsz);
  csum_k<<<dim3(4 * NCLS), dim3(256), 0, stream>>>(x, buckets, offsets, counts,
                                                   centers4, scal);
  cnorm_k<<<dim3(NCLS), dim3(256), 0, stream>>>(centers4, centers, counts,
                                                &scal[1]);

  // collapsed biases: biascat = [b0 | b1 + W1 b0 | b2 + W2 c1] (fp32 exact)
  matvec_k<<<dim3(N1), dim3(256), 0, stream>>>(W1, b0, b1, biascat + N0, N0);
  matvec_k<<<dim3(N2), dim3(256), 0, stream>>>(W2, biascat + N0, b2, biascat + N0 + N1, N1);

  // collapsed weights (fp8): M1 = W1@W0 -> Bcat8 seg1 + M1t8; M2 = W2@M1 -> seg2
  gemm8_w<<<dim3(D / 128, N1 / 128), dim3(256), 0, stream>>>(
      W1_8, W0t8, N1, D, N0, Bcat8 + (size_t)N0 * D, M1t8);
  gemm8_w<<<dim3(D / 128, N2 / 128), dim3(256), 0, stream>>>(
      W2_8, M1t8, N2, D, N1, Bcat8 + (size_t)(N0 + N1) * D, nullptr);

  // row-major -> fragment-major (LDS-friendly lo/hi split)
  reorder_k<<<dim3(Ncat * D / 32 / 256), dim3(256), 0, stream>>>(Bcat8, Bp);

  // pk via class-sum identity (needs Bcat8 complete + centers + biascat + counts)
  pk_k<<<dim3(3 * NCLS), dim3(64), 0, stream>>>(centers, Bcat8, biascat,
                                                counts, scal);

  // LDS-shared streaming fused logits+CE (all three levels), 2 blocks/CU
  gemm_ce8<<<dim3(Bsz / 128), dim3(256), 0, stream>>>(x, Bp, biascat, scal);

  fin_k<<<dim3(1), dim3(64), 0, stream>>>(scal, lam, (float*)d_out, 1.f / (float)Bsz);
}